// Round 5
// baseline (169.803 us; speedup 1.0000x reference)
//
#include <hip/hip_runtime.h>
#include <math.h>

#define NBATCH 8192
#define NNEI 256
#define NROLE 3
#define NHID 32
#define NDIM 6
#define NPERS 2048  // persistent blocks = 8/CU (observed WG cap) x 256 CUs
#define NBPB 4      // batches per block = NBATCH / NPERS

typedef float v2f __attribute__((ext_vector_type(2)));
typedef unsigned long long ull;

// Compiler-fenced lgkm-only barrier (CK "block_sync_lds" idiom): unlike
// __syncthreads(), does NOT drain vmcnt — prefetch loads stay in flight.
// imm 0xC07F: vmcnt=63, expcnt=7, lgkmcnt=0.
__device__ __forceinline__ void barrier_lds_only() {
  __asm__ __volatile__("" ::: "memory");
  __builtin_amdgcn_s_waitcnt(0xC07F);
  __builtin_amdgcn_s_barrier();
  __asm__ __volatile__("" ::: "memory");
}

// MLP score via packed-f32 pairs (v_pk_fma_f32): Linear(6,32)->ReLU->Linear(32,1).
// Weight pointers MUST be wave-uniform (readfirstlane'd role) so weight reads
// stay s_load scalar traffic — R5 showed losing this costs 4x.
__device__ __forceinline__ float mlp_score(const float x0, const float x1,
                                           const float x2, const float x3,
                                           const float x4, const float x5,
                                           const float* __restrict__ w1,
                                           const float* __restrict__ bb,
                                           const float* __restrict__ w2,
                                           const float b2v) {
  const float x[NDIM] = {x0, x1, x2, x3, x4, x5};
  v2f ac0 = {0.f, 0.f}, ac1 = {0.f, 0.f}, ac2 = {0.f, 0.f}, ac3 = {0.f, 0.f};
#pragma unroll
  for (int h = 0; h < NHID; h += 8) {
    v2f a0 = *(const v2f*)(bb + h + 0);
    v2f a1 = *(const v2f*)(bb + h + 2);
    v2f a2 = *(const v2f*)(bb + h + 4);
    v2f a3 = *(const v2f*)(bb + h + 6);
#pragma unroll
    for (int d = 0; d < NDIM; ++d) {
      const float xv = x[d];
      const v2f xv2 = {xv, xv};
      const float* wc = w1 + d * NHID + h;  // uniform addr -> s_load
      a0 += xv2 * (*(const v2f*)(wc + 0));  // -ffp-contract -> v_pk_fma_f32
      a1 += xv2 * (*(const v2f*)(wc + 2));
      a2 += xv2 * (*(const v2f*)(wc + 4));
      a3 += xv2 * (*(const v2f*)(wc + 6));
    }
    a0.x = fmaxf(a0.x, 0.f); a0.y = fmaxf(a0.y, 0.f);
    a1.x = fmaxf(a1.x, 0.f); a1.y = fmaxf(a1.y, 0.f);
    a2.x = fmaxf(a2.x, 0.f); a2.y = fmaxf(a2.y, 0.f);
    a3.x = fmaxf(a3.x, 0.f); a3.y = fmaxf(a3.y, 0.f);
    ac0 += a0 * (*(const v2f*)(w2 + h + 0));
    ac1 += a1 * (*(const v2f*)(w2 + h + 2));
    ac2 += a2 * (*(const v2f*)(w2 + h + 4));
    ac3 += a3 * (*(const v2f*)(w2 + h + 6));
  }
  const v2f st = (ac0 + ac1) + (ac2 + ac3);
  return b2v + st.x + st.y;
}

struct ChunkRegs {
  int rl, mk;
  float tw;
  float2 a, b, c;
};

// Issue the coalesced loads for one 64-neighbor chunk into registers.
// Placed EARLY (one batch ahead); compiler issues here, waits at first use.
__device__ __forceinline__ void load_chunk(const float* __restrict__ states,
                                           const int* __restrict__ roles,
                                           const int* __restrict__ maskp,
                                           const float* __restrict__ trust,
                                           const size_t rowb, const int chunk,
                                           const int lane, ChunkRegs& r) {
  const size_t gi = rowb + (size_t)(chunk * 64 + lane);
  r.rl = roles[gi];
  r.mk = maskp[gi];
  r.tw = trust[gi];
  const float* sp = states + gi * (size_t)NDIM;
  r.a = *(const float2*)(sp);
  r.b = *(const float2*)(sp + 2);
  r.c = *(const float2*)(sp + 4);
}

// Ballot-count + role-sorted SoA scatter for one chunk. SoA arrays are 1KB
// apart (256*k floats): bank = pos mod 32, positions dense -> ~2 lanes/bank
// (free, m136). No padding needed.
__device__ __forceinline__ void scatter_chunk(float* __restrict__ sbuf,
                                              int* __restrict__ scnt,
                                              const int chunk, const int lane,
                                              const ChunkRegs& r) {
  const bool active = (r.mk != 0);
  const ull bal0 = __ballot(active && (r.rl == 0));
  const ull bal1 = __ballot(active && (r.rl == 1));
  const ull bal2 = __ballot(active && (r.rl == 2));
  const int n0 = __popcll(bal0);
  const int n1 = __popcll(bal1);
  if (lane < 3) {
    const int n2 = __popcll(bal2);
    scnt[chunk * 3 + lane] = (lane == 0) ? n0 : (lane == 1) ? n1 : n2;
  }
  if (active) {
    const ull mybal = (r.rl == 0) ? bal0 : (r.rl == 1) ? bal1 : bal2;
    const int rank = __popcll(mybal & ((1ull << lane) - 1ull));
    const int pre = ((r.rl >= 1) ? n0 : 0) + ((r.rl >= 2) ? n1 : 0);
    const int pos = chunk * 64 + pre + rank;  // chunk-segmented dense
    sbuf[0 * NNEI + pos] = r.a.x;
    sbuf[1 * NNEI + pos] = r.a.y;
    sbuf[2 * NNEI + pos] = r.b.x;
    sbuf[3 * NNEI + pos] = r.b.y;
    sbuf[4 * NNEI + pos] = r.c.x;
    sbuf[5 * NNEI + pos] = r.c.y;
    sbuf[6 * NNEI + pos] = r.tw;
  }
}

// One role-pass: wave rw computes role rw's moment-fusion for one batch.
// Softmax max-subtraction cancels exactly in mf = sum(e*tw*v)/sum(e*tw)
// (exp(-m) divides out; only the 1e-8 epsilons break it, ~1e-10 relative;
// scores are O(1..12) so exp cannot overflow) — so we skip the max chain.
__device__ __forceinline__ void role_pass(const float* __restrict__ sbuf,
                                          const int* __restrict__ scnt,
                                          const int rw, const int lane,
                                          const float* __restrict__ w1,
                                          const float* __restrict__ bb,
                                          const float* __restrict__ w2,
                                          const float b2v,
                                          float* __restrict__ outp) {
  int cwv[4], prw[4];
#pragma unroll
  for (int w = 0; w < 4; ++w) {
    const int a0 = scnt[w * 3 + 0];
    const int a1 = scnt[w * 3 + 1];
    const int a2 = scnt[w * 3 + 2];
    const int cv = (rw == 0) ? a0 : (rw == 1) ? a1 : a2;
    const int pv = ((rw >= 1) ? a0 : 0) + ((rw >= 2) ? a1 : 0);
    cwv[w] = __builtin_amdgcn_readfirstlane(cv);
    prw[w] = __builtin_amdgcn_readfirstlane(pv);
  }
  const int acc0 = cwv[0];
  const int acc1 = acc0 + cwv[1];
  const int acc2 = acc1 + cwv[2];
  const int cnt = acc2 + cwv[3];

  float q0, q1, q2, q3, q4, q5, q6, q7;  // {Se, Set, Sd0..Sd5}

  if (cnt <= 64) {
    // ---- FAST PATH (P ~ 1 - 1e-4): single 64-lane pass ----
    const bool act = lane < cnt;
    const bool s1 = lane >= acc0;
    const bool s2 = lane >= acc1;
    const bool s3 = lane >= acc2;
    int sub = s1 ? acc0 : 0; sub = s2 ? acc1 : sub; sub = s3 ? acc2 : sub;
    int wb = s1 ? 64 : 0;    wb = s2 ? 128 : wb;    wb = s3 ? 192 : wb;
    int pr = s1 ? prw[1] : prw[0]; pr = s2 ? prw[2] : pr; pr = s3 ? prw[3] : pr;
    int pos = wb + pr + (lane - sub);
    pos = (pos > NNEI - 1) ? (NNEI - 1) : pos;  // inactive lanes may overrun
    pos = (pos < 0) ? 0 : pos;
    float x0 = sbuf[0 * NNEI + pos];
    float x1 = sbuf[1 * NNEI + pos];
    float x2 = sbuf[2 * NNEI + pos];
    float x3 = sbuf[3 * NNEI + pos];
    float x4 = sbuf[4 * NNEI + pos];
    float x5 = sbuf[5 * NNEI + pos];
    float tw = sbuf[6 * NNEI + pos];
    if (!act) {  // select-gate: unwritten slots may hold NaN
      x0 = x1 = x2 = x3 = x4 = x5 = tw = 0.f;
    }
    const float sc = mlp_score(x0, x1, x2, x3, x4, x5, w1, bb, w2, b2v);
    const float e = act ? __expf(sc) : 0.f;
    const float et = e * tw;
    q0 = e; q1 = et;
    q2 = et * x0; q3 = et * x1; q4 = et * x2;
    q5 = et * x3; q6 = et * x4; q7 = et * x5;
  } else {
    // ---- SLOW PATH (cold, ~3 lists in 24576): dynamic chunk loop ----
    q0 = q1 = q2 = q3 = q4 = q5 = q6 = q7 = 0.f;
    const int nch = (cnt + 63) >> 6;
    for (int c = 0; c < nch; ++c) {
      const int jj = c * 64 + lane;
      const bool act = jj < cnt;
      const bool s1 = jj >= acc0;
      const bool s2 = jj >= acc1;
      const bool s3 = jj >= acc2;
      int sub = s1 ? acc0 : 0; sub = s2 ? acc1 : sub; sub = s3 ? acc2 : sub;
      int wb = s1 ? 64 : 0;    wb = s2 ? 128 : wb;    wb = s3 ? 192 : wb;
      int pr = s1 ? prw[1] : prw[0]; pr = s2 ? prw[2] : pr; pr = s3 ? prw[3] : pr;
      int pos = wb + pr + (jj - sub);
      pos = (pos > NNEI - 1) ? (NNEI - 1) : pos;
      pos = (pos < 0) ? 0 : pos;
      float x0 = sbuf[0 * NNEI + pos];
      float x1 = sbuf[1 * NNEI + pos];
      float x2 = sbuf[2 * NNEI + pos];
      float x3 = sbuf[3 * NNEI + pos];
      float x4 = sbuf[4 * NNEI + pos];
      float x5 = sbuf[5 * NNEI + pos];
      float tw = sbuf[6 * NNEI + pos];
      if (!act) {
        x0 = x1 = x2 = x3 = x4 = x5 = tw = 0.f;
      }
      const float sc = mlp_score(x0, x1, x2, x3, x4, x5, w1, bb, w2, b2v);
      const float e = act ? __expf(sc) : 0.f;
      const float et = e * tw;
      q0 += e; q1 += et;
      q2 = fmaf(et, x0, q2); q3 = fmaf(et, x1, q3);
      q4 = fmaf(et, x2, q4); q5 = fmaf(et, x3, q5);
      q6 = fmaf(et, x4, q6); q7 = fmaf(et, x5, q7);
    }
  }

  // ---- reduction: 3 xor steps x8 (independent), select, 3 xor steps x1 ----
#pragma unroll
  for (int off = 1; off <= 4; off <<= 1) {
    q0 += __shfl_xor(q0, off); q1 += __shfl_xor(q1, off);
    q2 += __shfl_xor(q2, off); q3 += __shfl_xor(q3, off);
    q4 += __shfl_xor(q4, off); q5 += __shfl_xor(q5, off);
    q6 += __shfl_xor(q6, off); q7 += __shfl_xor(q7, off);
  }
  const int g = lane & 7;
  float myq = q0;
  myq = (g == 1) ? q1 : myq;
  myq = (g == 2) ? q2 : myq;
  myq = (g == 3) ? q3 : myq;
  myq = (g == 4) ? q4 : myq;
  myq = (g == 5) ? q5 : myq;
  myq = (g == 6) ? q6 : myq;
  myq = (g == 7) ? q7 : myq;
  myq += __shfl_xor(myq, 8);
  myq += __shfl_xor(myq, 16);
  myq += __shfl_xor(myq, 32);
  // lane i now holds the 64-lane total of quantity (i & 7)
  const float Se = __shfl(myq, 0);
  const float Set = __shfl(myq, 1);
  const float denom = Se + 1e-8f;
  const float ws = fmaxf(Set / denom, 1e-8f);
  if (lane >= 2 && lane < 8) {
    outp[rw * NDIM + (lane - 2)] = (myq / denom) / ws;
  }
}

// Persistent double-buffered pipeline (T14 async-stage split):
//   grid = 2048 blocks (8/CU, the observed WG cap), 4 batches each.
//   Iteration t: [regs for batch t+1 already in flight] -> lgkm-barrier ->
//   role_pass on buf[t&1] (~1500+ cy, hides the HBM round-trip) -> consume
//   t+1 regs (vmcnt wait is now free), ballot+scatter into buf[(t+1)&1] ->
//   issue loads for batch t+2. One barrier per iteration; vm loads stay in
//   flight across it (barrier_lds_only).
// Race-safety: wave B passes barrier(t) only after its role_pass(t-1) LDS
// reads drained (lgkmcnt(0) before s_barrier), so wave A's scatter(t+1) into
// the other buffer never races a reader of the buffer it overwrites.
__global__ __launch_bounds__(192, 6) void hmf_main(
    const float* __restrict__ states,
    const int* __restrict__ roles,
    const int* __restrict__ maskp,   // bool arrives as int32
    const float* __restrict__ trust,
    const float* __restrict__ W1,    // [R][D][H]
    const float* __restrict__ b1,    // [R][H]
    const float* __restrict__ W2,    // [R][H]
    const float* __restrict__ b2g,   // [R]
    float* __restrict__ out) {
  const int tid = threadIdx.x;
  const int wave = tid >> 6;  // 0..2
  const int lane = tid & 63;

  __shared__ float soa[2][7 * NNEI];  // 2 x 7 KB SoA (s0..s5, tw)
  __shared__ int scnt[2][12];         // [buf][chunk*3 + role]

  const int rw = __builtin_amdgcn_readfirstlane(wave);
  const float* w1 = W1 + rw * (NDIM * NHID);
  const float* bb = b1 + rw * NHID;
  const float* w2 = W2 + rw * NHID;
  const float b2v = b2g[rw];
  const bool dual = (wave == 0);  // wave 0 owns chunks 0 and 3

  // ---- prologue: batch 0 load+scatter, then issue batch-1 loads ----
  ChunkRegs cr0, cr1;
  size_t rowb = (size_t)blockIdx.x * NNEI;
  load_chunk(states, roles, maskp, trust, rowb, wave, lane, cr0);
  if (dual) load_chunk(states, roles, maskp, trust, rowb, 3, lane, cr1);
  scatter_chunk(&soa[0][0], scnt[0], wave, lane, cr0);
  if (dual) scatter_chunk(&soa[0][0], scnt[0], 3, lane, cr1);
  rowb = (size_t)(blockIdx.x + NPERS) * NNEI;
  load_chunk(states, roles, maskp, trust, rowb, wave, lane, cr0);
  if (dual) load_chunk(states, roles, maskp, trust, rowb, 3, lane, cr1);

#pragma unroll
  for (int t = 0; t < NBPB; ++t) {
    const int buf = t & 1;
    barrier_lds_only();
    const int b = blockIdx.x + t * NPERS;
    role_pass(&soa[buf][0], scnt[buf], rw, lane, w1, bb, w2, b2v,
              out + (size_t)b * (NROLE * NDIM));
    if (t + 1 < NBPB) {
      scatter_chunk(&soa[buf ^ 1][0], scnt[buf ^ 1], wave, lane, cr0);
      if (dual) scatter_chunk(&soa[buf ^ 1][0], scnt[buf ^ 1], 3, lane, cr1);
      if (t + 2 < NBPB) {
        rowb = (size_t)(blockIdx.x + (t + 2) * NPERS) * NNEI;
        load_chunk(states, roles, maskp, trust, rowb, wave, lane, cr0);
        if (dual) load_chunk(states, roles, maskp, trust, rowb, 3, lane, cr1);
      }
    }
  }
}

extern "C" void kernel_launch(void* const* d_in, const int* in_sizes, int n_in,
                              void* d_out, int out_size, void* d_ws, size_t ws_size,
                              hipStream_t stream) {
  const float* states = (const float*)d_in[0];
  const int* roles = (const int*)d_in[1];
  const int* maskp = (const int*)d_in[2];
  const float* trust = (const float*)d_in[3];
  const float* W1 = (const float*)d_in[4];
  const float* b1 = (const float*)d_in[5];
  const float* W2 = (const float*)d_in[6];
  const float* b2 = (const float*)d_in[7];
  float* out = (float*)d_out;

  hmf_main<<<NPERS, 192, 0, stream>>>(states, roles, maskp, trust, W1, b1, W2, b2, out);
}

// Round 6
// 118.762 us; speedup vs baseline: 1.4298x; 1.4298x over previous
//
#include <hip/hip_runtime.h>
#include <math.h>

#define NBATCH 8192
#define NNEI 256
#define NROLE 3
#define NHID 32
#define NDIM 6
// 48B record stride: record p's b128 lands in 16B-bank-group (3p mod 8) — a
// perfect permutation over all 8 groups -> near-conflict-free for b128/b64/b32.
#define SSTRIDE 12

typedef float v2f __attribute__((ext_vector_type(2)));
typedef unsigned long long ull;

// Compiler-fenced lgkm-only barrier (CK "block_sync_lds" idiom): unlike
// __syncthreads(), does NOT drain vmcnt — any global loads stay in flight.
// imm 0xC07F: vmcnt=63, expcnt=7, lgkmcnt=0.
__device__ __forceinline__ void barrier_lds_only() {
  __asm__ __volatile__("" ::: "memory");
  __builtin_amdgcn_s_waitcnt(0xC07F);
  __builtin_amdgcn_s_barrier();
  __asm__ __volatile__("" ::: "memory");
}

// DPP lane-shift move (VALU-only, no DS pipe, no address setup).
// bound_ctrl=true -> out-of-range source lanes produce 0 (safe for sums).
template <int CTRL>
__device__ __forceinline__ float dppmov(float x) {
  return __int_as_float(__builtin_amdgcn_update_dpp(
      0, __float_as_int(x), CTRL, 0xF, 0xF, true));
}

// 64-lane sum via DPP prefix reduction: after row_shr 1/2/4/8 each 16-row's
// lane15 holds the row total; row_bcast15 then row_bcast31 accumulate rows.
// Lane 63 holds the full total. Replaces 6 ds_bpermute levels (DS pipe +
// ~26cy/level latency) with 6 VALU adds.
__device__ __forceinline__ float wavesum_dpp(float v) {
  v += dppmov<0x111>(v);  // row_shr:1
  v += dppmov<0x112>(v);  // row_shr:2
  v += dppmov<0x114>(v);  // row_shr:4
  v += dppmov<0x118>(v);  // row_shr:8
  v += dppmov<0x142>(v);  // row_bcast:15
  v += dppmov<0x143>(v);  // row_bcast:31
  return v;               // lane 63 = total
}
__device__ __forceinline__ float total63(float v) {
  return __int_as_float(
      __builtin_amdgcn_readlane(__float_as_int(wavesum_dpp(v)), 63));
}

// MLP score via packed-f32 pairs (v_pk_fma_f32): Linear(6,32)->ReLU->Linear(32,1).
// Weight pointers MUST be wave-uniform (readfirstlane'd role) so weight reads
// stay s_load scalar traffic — R5 showed losing this costs 4x.
__device__ __forceinline__ float mlp_score(const float x0, const float x1,
                                           const float x2, const float x3,
                                           const float x4, const float x5,
                                           const float* __restrict__ w1,
                                           const float* __restrict__ bb,
                                           const float* __restrict__ w2,
                                           const float b2v) {
  const float x[NDIM] = {x0, x1, x2, x3, x4, x5};
  v2f ac0 = {0.f, 0.f}, ac1 = {0.f, 0.f}, ac2 = {0.f, 0.f}, ac3 = {0.f, 0.f};
#pragma unroll
  for (int h = 0; h < NHID; h += 8) {
    v2f a0 = *(const v2f*)(bb + h + 0);
    v2f a1 = *(const v2f*)(bb + h + 2);
    v2f a2 = *(const v2f*)(bb + h + 4);
    v2f a3 = *(const v2f*)(bb + h + 6);
#pragma unroll
    for (int d = 0; d < NDIM; ++d) {
      const float xv = x[d];
      const v2f xv2 = {xv, xv};
      const float* wc = w1 + d * NHID + h;  // uniform addr -> s_load
      a0 += xv2 * (*(const v2f*)(wc + 0));  // -ffp-contract -> v_pk_fma_f32
      a1 += xv2 * (*(const v2f*)(wc + 2));
      a2 += xv2 * (*(const v2f*)(wc + 4));
      a3 += xv2 * (*(const v2f*)(wc + 6));
    }
    a0.x = fmaxf(a0.x, 0.f); a0.y = fmaxf(a0.y, 0.f);
    a1.x = fmaxf(a1.x, 0.f); a1.y = fmaxf(a1.y, 0.f);
    a2.x = fmaxf(a2.x, 0.f); a2.y = fmaxf(a2.y, 0.f);
    a3.x = fmaxf(a3.x, 0.f); a3.y = fmaxf(a3.y, 0.f);
    ac0 += a0 * (*(const v2f*)(w2 + h + 0));
    ac1 += a1 * (*(const v2f*)(w2 + h + 2));
    ac2 += a2 * (*(const v2f*)(w2 + h + 4));
    ac3 += a3 * (*(const v2f*)(w2 + h + 6));
  }
  const v2f st = (ac0 + ac1) + (ac2 + ac3);
  return b2v + st.x + st.y;
}

// 192-thread blocks (3 waves): wave r owns role r in phase 3 -> no idle wave.
// Wave 0 additionally handles chunk 3 in phase 1 (loads issued together, so
// latency overlaps; waves 1-2 just reach the barrier early).
// Softmax max-subtraction cancels exactly in mf = sum(e*tw*v)/sum(e*tw)
// (exp(-m) divides out; only the 1e-8 epsilons break it, ~1e-10 relative;
// scores are O(1..12) so exp cannot overflow) — so we skip the max chain.
__global__ __launch_bounds__(192) void hmf_main(
    const float* __restrict__ states,
    const int* __restrict__ roles,
    const int* __restrict__ maskp,   // bool arrives as int32
    const float* __restrict__ trust,
    const float* __restrict__ W1,    // [R][D][H]
    const float* __restrict__ b1,    // [R][H]
    const float* __restrict__ W2,    // [R][H]
    const float* __restrict__ b2g,   // [R]
    float* __restrict__ out) {
  const int b = blockIdx.x;
  const int tid = threadIdx.x;
  const int wave = tid >> 6;   // 0..2
  const int lane = tid & 63;

  __shared__ float ssort[NNEI * SSTRIDE];       // 12 KB; chunk c owns [64c,64c+64)
  __shared__ alignas(16) int scnt4[4];          // packed c0|c1<<8|c2<<16 per chunk

  const size_t rowb = (size_t)b * NNEI;

  // ---- phase 1: coalesced loads, per-role ballots, per-chunk sorted scatter ----
  // chunk A = wave; chunk B = 3 (wave 0 only). Issue ALL loads before ballots.
  const size_t idxA = rowb + (size_t)(wave * 64 + lane);
  const int roleA = roles[idxA];
  const int maskA = maskp[idxA];
  const float twA = trust[idxA];
  const float* spA = states + idxA * (size_t)NDIM;
  const float2 aA = *(const float2*)(spA);
  const float2 aB = *(const float2*)(spA + 2);
  const float2 aC = *(const float2*)(spA + 4);

  const bool have2 = (wave == 0);
  int roleB = 0, maskB = 0;
  float twB = 0.f;
  float2 bA = {0.f, 0.f}, bB = {0.f, 0.f}, bC = {0.f, 0.f};
  if (have2) {
    const size_t idxB = rowb + (size_t)(192 + lane);
    roleB = roles[idxB];
    maskB = maskp[idxB];
    twB = trust[idxB];
    const float* spB = states + idxB * (size_t)NDIM;
    bA = *(const float2*)(spB);
    bB = *(const float2*)(spB + 2);
    bC = *(const float2*)(spB + 4);
  }

  {  // chunk A (c = wave)
    const bool active = (maskA != 0);
    const ull bal0 = __ballot(active && (roleA == 0));
    const ull bal1 = __ballot(active && (roleA == 1));
    const ull bal2 = __ballot(active && (roleA == 2));
    const int c0 = __popcll(bal0);
    const int c1 = __popcll(bal1);
    const int c2 = __popcll(bal2);
    if (lane == 0) scnt4[wave] = c0 | (c1 << 8) | (c2 << 16);
    if (active) {
      const ull mybal = (roleA == 0) ? bal0 : (roleA == 1) ? bal1 : bal2;
      const int rank = __popcll(mybal & ((1ull << lane) - 1ull));
      const int pre = ((roleA >= 1) ? c0 : 0) + ((roleA >= 2) ? c1 : 0);
      const int pos = wave * 64 + pre + rank;  // chunk-private region
      float* dst = ssort + pos * SSTRIDE;
      *(float4*)dst = make_float4(aA.x, aA.y, aB.x, aB.y);
      *(float4*)(dst + 4) = make_float4(aC.x, aC.y, twA, 0.f);
    }
  }
  if (have2) {  // chunk B (c = 3), wave 0 only — ballots are whole-wave here
    const bool active = (maskB != 0);
    const ull bal0 = __ballot(active && (roleB == 0));
    const ull bal1 = __ballot(active && (roleB == 1));
    const ull bal2 = __ballot(active && (roleB == 2));
    const int c0 = __popcll(bal0);
    const int c1 = __popcll(bal1);
    const int c2 = __popcll(bal2);
    if (lane == 0) scnt4[3] = c0 | (c1 << 8) | (c2 << 16);
    if (active) {
      const ull mybal = (roleB == 0) ? bal0 : (roleB == 1) ? bal1 : bal2;
      const int rank = __popcll(mybal & ((1ull << lane) - 1ull));
      const int pre = ((roleB >= 1) ? c0 : 0) + ((roleB >= 2) ? c1 : 0);
      const int pos = 192 + pre + rank;
      float* dst = ssort + pos * SSTRIDE;
      *(float4*)dst = make_float4(bA.x, bA.y, bB.x, bB.y);
      *(float4*)(dst + 4) = make_float4(bC.x, bC.y, twB, 0.f);
    }
  }
  barrier_lds_only();  // the ONLY barrier

  // ---- phase 3: wave r handles role r across the 4 chunk-segments ----
  {
    const int r = __builtin_amdgcn_readfirstlane(wave);
    const int4 scv = *(const int4*)scnt4;  // single ds_read_b128
    int cwv[4], prw[4];
#pragma unroll
    for (int w = 0; w < 4; ++w) {
      const int pk = __builtin_amdgcn_readfirstlane((&scv.x)[w]);
      const int a0 = pk & 0xFF;
      const int a1 = (pk >> 8) & 0xFF;
      const int a2 = (pk >> 16) & 0xFF;
      cwv[w] = (r == 0) ? a0 : (r == 1) ? a1 : a2;
      prw[w] = ((r >= 1) ? a0 : 0) + ((r >= 2) ? a1 : 0);
    }
    const int acc0 = cwv[0];
    const int acc1 = acc0 + cwv[1];
    const int acc2 = acc1 + cwv[2];
    const int cnt = acc2 + cwv[3];

    const float* w1 = W1 + r * (NDIM * NHID);
    const float* bb = b1 + r * NHID;
    const float* w2 = W2 + r * NHID;
    const float b2v = b2g[r];

    float q0, q1, q2, q3, q4, q5, q6, q7;  // {Se, Set, Sd0..Sd5}

    if (cnt <= 64) {
      // ---- FAST PATH (P ~ 1 - 1e-4): single chunk, static control flow ----
      const bool act = lane < cnt;
      const bool s1 = lane >= acc0;
      const bool s2 = lane >= acc1;
      const bool s3 = lane >= acc2;
      int sub = s1 ? acc0 : 0; sub = s2 ? acc1 : sub; sub = s3 ? acc2 : sub;
      int wb = s1 ? 64 : 0;    wb = s2 ? 128 : wb;    wb = s3 ? 192 : wb;
      int pr = s1 ? prw[1] : prw[0]; pr = s2 ? prw[2] : pr; pr = s3 ? prw[3] : pr;
      int pos = wb + pr + (lane - sub);
      pos = (pos > NNEI - 1) ? (NNEI - 1) : pos;  // inactive lanes may overrun
      const float* s = ssort + pos * SSTRIDE;
      float4 v4 = *(const float4*)s;
      float4 vb = *(const float4*)(s + 4);
      float tw = vb.z;
      if (!act) {  // select-gate: garbage slots may hold NaN
        v4 = make_float4(0.f, 0.f, 0.f, 0.f);
        vb = make_float4(0.f, 0.f, 0.f, 0.f);
        tw = 0.f;
      }
      const float sc = mlp_score(v4.x, v4.y, v4.z, v4.w, vb.x, vb.y, w1, bb, w2, b2v);
      const float e = act ? __expf(sc) : 0.f;
      const float et = e * tw;
      q0 = e; q1 = et;
      q2 = et * v4.x; q3 = et * v4.y; q4 = et * v4.z;
      q5 = et * v4.w; q6 = et * vb.x; q7 = et * vb.y;
    } else {
      // ---- SLOW PATH (cold, ~3 lists in 24576): dynamic chunk loop ----
      q0 = q1 = q2 = q3 = q4 = q5 = q6 = q7 = 0.f;
      const int nch = (cnt + 63) >> 6;
      for (int c = 0; c < nch; ++c) {
        const int jj = c * 64 + lane;
        const bool act = jj < cnt;
        const bool s1 = jj >= acc0;
        const bool s2 = jj >= acc1;
        const bool s3 = jj >= acc2;
        int sub = s1 ? acc0 : 0; sub = s2 ? acc1 : sub; sub = s3 ? acc2 : sub;
        int wb = s1 ? 64 : 0;    wb = s2 ? 128 : wb;    wb = s3 ? 192 : wb;
        int pr = s1 ? prw[1] : prw[0]; pr = s2 ? prw[2] : pr; pr = s3 ? prw[3] : pr;
        int pos = wb + pr + (jj - sub);
        pos = (pos > NNEI - 1) ? (NNEI - 1) : pos;
        pos = (pos < 0) ? 0 : pos;
        const float* s = ssort + pos * SSTRIDE;
        float4 v4 = *(const float4*)s;
        float4 vb = *(const float4*)(s + 4);
        float tw = vb.z;
        if (!act) {
          v4 = make_float4(0.f, 0.f, 0.f, 0.f);
          vb = make_float4(0.f, 0.f, 0.f, 0.f);
          tw = 0.f;
        }
        const float sc = mlp_score(v4.x, v4.y, v4.z, v4.w, vb.x, vb.y, w1, bb, w2, b2v);
        const float e = act ? __expf(sc) : 0.f;
        const float et = e * tw;
        q0 += e; q1 += et;
        q2 = fmaf(et, v4.x, q2); q3 = fmaf(et, v4.y, q3);
        q4 = fmaf(et, v4.z, q4); q5 = fmaf(et, v4.w, q5);
        q6 = fmaf(et, vb.x, q6); q7 = fmaf(et, vb.y, q7);
      }
    }

    // ---- reduction: 8 independent DPP prefix-sums (VALU-only, no DS pipe),
    // totals read from lane 63 into SGPRs ----
    const float Se  = total63(q0);
    const float Set = total63(q1);
    const float T2  = total63(q2);
    const float T3  = total63(q3);
    const float T4  = total63(q4);
    const float T5  = total63(q5);
    const float T6  = total63(q6);
    const float T7  = total63(q7);

    const float denom = Se + 1e-8f;
    const float ws = fmaxf(Set / denom, 1e-8f);
    const float scale = 1.0f / (denom * ws);  // one div (uniform) vs 12 lane-divs
    if (lane >= 2 && lane < 8) {
      float num = T2;
      num = (lane == 3) ? T3 : num;
      num = (lane == 4) ? T4 : num;
      num = (lane == 5) ? T5 : num;
      num = (lane == 6) ? T6 : num;
      num = (lane == 7) ? T7 : num;
      out[(size_t)b * (NROLE * NDIM) + r * NDIM + (lane - 2)] = num * scale;
    }
  }
}

extern "C" void kernel_launch(void* const* d_in, const int* in_sizes, int n_in,
                              void* d_out, int out_size, void* d_ws, size_t ws_size,
                              hipStream_t stream) {
  const float* states = (const float*)d_in[0];
  const int* roles = (const int*)d_in[1];
  const int* maskp = (const int*)d_in[2];
  const float* trust = (const float*)d_in[3];
  const float* W1 = (const float*)d_in[4];
  const float* b1 = (const float*)d_in[5];
  const float* W2 = (const float*)d_in[6];
  const float* b2 = (const float*)d_in[7];
  float* out = (float*)d_out;

  hmf_main<<<NBATCH, 192, 0, stream>>>(states, roles, maskp, trust, W1, b1, W2, b2, out);
}